// Round 16
// baseline (717.552 us; speedup 1.0000x reference)
//
#include <hip/hip_runtime.h>
#include <hip/hip_fp16.h>
#include <stdint.h>

#define B_ROWS 4096
#define D_IN   1024
#define H_HID  16384
#define K_TOP  32

#define NT       64       // H_HID/256 tn-tiles per row
#define GROWS    8192     // 2*B_ROWS
#define SLOT     32       // per-(row, tn-tile) fixed segment slots (mean 10.7, s 3.2)
#define CAND_CAP 1536     // per-row gathered candidate cap (mean 682, s 26)
#define TAU      1.0f     // fixed candidate threshold; safety via flags+fallback
#define TK_DELTA 1e-2f    // refinement window half-width (>= 2x 12-sigma h~ error)
#define WCAP     256

typedef __attribute__((ext_vector_type(8))) _Float16 half8;
typedef __attribute__((ext_vector_type(4))) float    f32x4;

// ---------------- helpers ----------------

__device__ __forceinline__ ushort hi16(float x) {
  return (fabsf(x) >= 0x1p-14f) ? __half_as_ushort(__float2half(x)) : (ushort)0;
}

__device__ __forceinline__ void gload_lds16(const void* g, void* l) {
  __builtin_amdgcn_global_load_lds(
      (const __attribute__((address_space(1))) void*)g,
      (__attribute__((address_space(3))) void*)l, 16, 0, 0);
}

// ---------------- fused prep: split_wt + split_a + zero + Wdec->f16 ----------
// grid: [0,32768) W_enc transpose/split | [32768,40960) X split |
//       [40960,43040) zero cntt+flags | [43040,59424) Wdec f32->f16
__global__ __launch_bounds__(256) void prep_kernel(
    const float* __restrict__ W0, const float* __restrict__ W1,
    ushort* __restrict__ hiT0, ushort* __restrict__ hiT1,
    float* __restrict__ wT0, float* __restrict__ wT1,
    const float* __restrict__ x0, const float* __restrict__ x1,
    ushort* __restrict__ hiA0, ushort* __restrict__ hiA1,
    int* __restrict__ zbase,
    const float* __restrict__ Wd0, const float* __restrict__ Wd1,
    ushort* __restrict__ Wd16_0, ushort* __restrict__ Wd16_1) {
  __shared__ float tile[32][33];
  const int b = blockIdx.x;
  const int tid = threadIdx.x;
  if (b < 32768) {                      // ---- W_enc transpose + split ----
    const int s  = b >> 14;
    const int b2 = b & 16383;           // 512 x 32
    const float* W = s ? W1 : W0;
    ushort* hiT = s ? hiT1 : hiT0;
    float*  wT32 = s ? wT1 : wT0;
    const int c0 = (b2 & 511) * 32;
    const int r0 = (b2 >> 9) * 32;
    const int tx = tid & 31;
    const int ty = tid >> 5;
#pragma unroll
    for (int i = 0; i < 32; i += 8)
      tile[ty + i][tx] = W[(size_t)(r0 + ty + i) * H_HID + c0 + tx];
    __syncthreads();
#pragma unroll
    for (int i = 0; i < 32; i += 8) {
      float v = tile[tx][ty + i];
      size_t o = (size_t)(c0 + ty + i) * D_IN + r0 + tx;
      hiT[o]  = hi16(v);
      wT32[o] = v;
    }
  } else if (b < 40960) {               // ---- X split ----
    const int idx = b - 32768;          // 0..8191; 4096 per stream
    const int s = idx >> 12;
    const float* x = s ? x1 : x0;
    ushort* hi = s ? hiA1 : hiA0;
    const int t = (idx & 4095) * 256 + tid;
    const int base = t * 4;
    float4 v = *reinterpret_cast<const float4*>(x + base);
    ushort4 h;
    h.x = hi16(v.x); h.y = hi16(v.y); h.z = hi16(v.z); h.w = hi16(v.w);
    *reinterpret_cast<ushort4*>(hi + base) = h;
  } else if (b < 43040) {               // ---- zero cntt+flags (532480 ints) ----
    const int idx = (b - 40960) * 256 + tid;
    zbase[idx] = 0;
  } else {                              // ---- Wdec f32 -> f16 (rows contiguous) ----
    const int idx = b - 43040;          // 0..16383; 8192 per stream
    const int s = idx >> 13;
    const float* Wd = s ? Wd1 : Wd0;
    ushort* Wd16 = s ? Wd16_1 : Wd16_0;
    const size_t base = ((size_t)(idx & 8191) * 256 + tid) * 8;
    const float4 v0 = *reinterpret_cast<const float4*>(Wd + base);
    const float4 v1 = *reinterpret_cast<const float4*>(Wd + base + 4);
    ushort4 h0, h1;
    h0.x = __half_as_ushort(__float2half(v0.x));
    h0.y = __half_as_ushort(__float2half(v0.y));
    h0.z = __half_as_ushort(__float2half(v0.z));
    h0.w = __half_as_ushort(__float2half(v0.w));
    h1.x = __half_as_ushort(__float2half(v1.x));
    h1.y = __half_as_ushort(__float2half(v1.y));
    h1.z = __half_as_ushort(__float2half(v1.z));
    h1.w = __half_as_ushort(__float2half(v1.w));
    *reinterpret_cast<ushort4*>(Wd16 + base)     = h0;
    *reinterpret_cast<ushort4*>(Wd16 + base + 4) = h1;
  }
}

// ---------------- encoder GEMM: 256x256 tiles, 8-phase, persistent J=8 -------
// (frozen: identical to R15 -- XCD-paired mapping, counted-vmcnt ledger)
#define NTILES 16   // 1024 / 64
#define JTILES 8

__global__ __launch_bounds__(512, 2) void gemm_enc_8ph(const ushort* __restrict__ Ah0,
                                                       const ushort* __restrict__ Ah1,
                                                       const ushort* __restrict__ Bh0,
                                                       const ushort* __restrict__ Bh1,
                                                       const float* __restrict__ bias0,
                                                       const float* __restrict__ bias1,
                                                       float2* __restrict__ cand_seg,
                                                       int* __restrict__ cntt,
                                                       int* __restrict__ flags) {
  extern __shared__ ushort smem[];   // [2][32768]: buf*32768, B-half at +16384
  __shared__ int lcnt[256];          // epilogue row counters (static, +1KB)
  const int tid  = threadIdx.x;
  const int wid  = tid >> 6;
  const int lane = tid & 63;
  const int wr   = wid >> 2;
  const int wc   = wid & 3;
  // XCD-paired decode: 4 (strm,tm) pairs per XCD, 8 tng blocks per pair
  const int xcd  = blockIdx.x & 7;
  const int slot = blockIdx.x >> 3;            // 0..31
  const int pair = xcd * 4 + (slot >> 3);      // 0..31 distinct (strm,tm)
  const int strm = pair >> 4;
  const int tm   = pair & 15;
  const int tng  = slot & 7;                   // 0..7 (group of 8 tn)
  const ushort* Ah = strm ? Ah1 : Ah0;
  const ushort* Bh = strm ? Bh1 : Bh0;
  const float* bias = strm ? bias1 : bias0;
  const int rowA0 = tm * 256;

  const int st_row = wid * 8 + (lane >> 3);
  const int st_lin = lane & 7;
  const int st_src = (lane & 7) ^ ((lane >> 3) & 7);
  const int fr   = lane & 15;
  const int fk   = lane >> 4;
  const int swz8 = (lane & 7) << 3;

  f32x4 acc[8][4];
#pragma unroll
  for (int i = 0; i < 8; ++i)
#pragma unroll
    for (int j = 0; j < 4; ++j) {
      f32x4 z = {0.f, 0.f, 0.f, 0.f};
      acc[i][j] = z;
    }
  half8 a[4][2], b[4][2];

#define DS_A(MH)                                                            \
  _Pragma("unroll") for (int m = 0; m < 4; ++m)                             \
  _Pragma("unroll") for (int k = 0; k < 2; ++k) {                           \
    const int r = wr * 128 + ((MH) * 4 + m) * 16 + fr;                      \
    const int idx = (r * 64 + k * 32 + fk * 8) ^ swz8;                      \
    a[m][k] = *reinterpret_cast<const half8*>(Acur + idx);                  \
  }
#define DS_B(NH)                                                            \
  _Pragma("unroll") for (int n = 0; n < 2; ++n)                             \
  _Pragma("unroll") for (int k = 0; k < 2; ++k) {                           \
    const int r = wc * 64 + ((NH) * 2 + n) * 16 + fr;                       \
    const int idx = (r * 64 + k * 32 + fk * 8) ^ swz8;                      \
    b[(NH) * 2 + n][k] = *reinterpret_cast<const half8*>(Bcur + idx);       \
  }
#define MFMA_PH(MH, NH)                                                     \
  __builtin_amdgcn_s_setprio(1);                                            \
  _Pragma("unroll") for (int m = 0; m < 4; ++m)                             \
  _Pragma("unroll") for (int n = 0; n < 2; ++n)                             \
  _Pragma("unroll") for (int k = 0; k < 2; ++k)                             \
    acc[(MH) * 4 + m][(NH) * 2 + n] = __builtin_amdgcn_mfma_f32_16x16x32_f16( \
        a[m][k], b[(NH) * 2 + n][k], acc[(MH) * 4 + m][(NH) * 2 + n], 0, 0, 0); \
  __builtin_amdgcn_s_setprio(0);
#define STAGE_A(Q)                                                          \
  gload_lds16(Ah + (size_t)(rowA0 + (Q) * 64 + st_row) * 1024 + st_k0 + st_src * 8, \
              Lnxt + ((Q) * 64 + st_row) * 64 + st_lin * 8)
#define STAGE_B(Q)                                                          \
  gload_lds16(Bh + (size_t)(st_rowB0 + (Q) * 64 + st_row) * 1024 + st_k0 + st_src * 8, \
              Lnxt + 16384 + ((Q) * 64 + st_row) * 64 + st_lin * 8)
#define BAR() __builtin_amdgcn_s_barrier()

  // prologue: stage (j=0, t=0) into buf0.  Order: Bq0..3, Aq0, Aq2, Aq1, Aq3.
  {
    const int st_k0 = 0;
    const int st_rowB0 = tng * 8 * 256;
    ushort* Lnxt = smem;
    STAGE_B(0); STAGE_B(1); STAGE_B(2); STAGE_B(3);
    STAGE_A(0); STAGE_A(2); STAGE_A(1); STAGE_A(3);
  }
  asm volatile("s_waitcnt vmcnt(2)" ::: "memory");
  BAR();

#pragma unroll 1
  for (int jt = 0; jt < JTILES * NTILES; ++jt) {
    const int t = jt & (NTILES - 1);
    const int j = jt >> 4;
    const int cur = t & 1;                     // NTILES even -> parity by t
    const ushort* Acur = smem + cur * 32768;
    const ushort* Bcur = Acur + 16384;
    ushort* Lnxt = smem + (cur ^ 1) * 32768;
    int tt = t + 1, jn = j;
    if (tt == NTILES) { tt = 0; jn = j + 1; }
    const bool hn = (jn < JTILES);
    const int st_k0 = tt << 6;
    const int st_rowB0 = (tng * 8 + jn) * 256;

    // phase 1
    DS_A(0); DS_B(0);
    if (hn) { STAGE_B(0); STAGE_B(1); }
    BAR();
    MFMA_PH(0, 0);
    BAR();
    // phase 2
    DS_B(1);
    if (hn) { STAGE_B(2); STAGE_B(3); }
    BAR();
    MFMA_PH(0, 1);
    asm volatile("s_waitcnt vmcnt(4)" ::: "memory");
    BAR();
    // phase 3
    DS_A(1);
    if (hn) { STAGE_A(0); STAGE_A(2); }
    BAR();
    MFMA_PH(1, 0);
    BAR();
    // phase 4
    if (hn) { STAGE_A(1); STAGE_A(3); }
    BAR();
    MFMA_PH(1, 1);
    asm volatile("s_waitcnt vmcnt(2)" ::: "memory");
    BAR();

    if (t == NTILES - 1) {
      // ---- candidate epilogue for tile (tm, tn = tng*8+j) ----
      const int tn = tng * 8 + j;
      float2* lcand = reinterpret_cast<float2*>(smem + 32768);  // [SLOT][256]
      if (tid < 256) lcnt[tid] = 0;
      __syncthreads();

      const int ccol = lane & 15;
      const int crow = (lane >> 4) * 4;
#pragma unroll
      for (int jj = 0; jj < 4; ++jj) {
        const int col = tn * 256 + wc * 64 + jj * 16 + ccol;
        const float bv = bias[col];
#pragma unroll
        for (int i = 0; i < 8; ++i) {
          const int lrow0 = wr * 128 + i * 16 + crow;
#pragma unroll
          for (int p = 0; p < 4; ++p) {
            const float v = acc[i][jj][p] + bv;
            if (v >= TAU) {
              const int lrow = lrow0 + p;
              const int pos = atomicAdd(&lcnt[lrow], 1);   // LDS atomic only
              if (pos < SLOT)
                lcand[pos * 256 + lrow] = make_float2(v, __int_as_float(col));
            }
          }
        }
      }
      __syncthreads();

      if (tid < 256) {
        int c = lcnt[tid];
        const int grow = strm * B_ROWS + rowA0 + tid;
        if (c > SLOT) { flags[grow] = 1; c = SLOT; }
        const size_t seg = (size_t)grow * NT + tn;       // [grow][tn] layout
        cntt[seg] = c;                                   // plain store
        float2* dst = cand_seg + seg * SLOT;
        for (int k = 0; k < c; ++k) dst[k] = lcand[k * 256 + tid];
      }
      // reset accumulators for the next tile
#pragma unroll
      for (int i = 0; i < 8; ++i)
#pragma unroll
        for (int jj = 0; jj < 4; ++jj) {
          f32x4 z = {0.f, 0.f, 0.f, 0.f};
          acc[i][jj] = z;
        }
      __syncthreads();   // lcand reads done before buf1 is restaged (next t=0 ph1)
    }
  }
#undef DS_A
#undef DS_B
#undef MFMA_PH
#undef STAGE_A
#undef STAGE_B
#undef BAR
}

// ---------------- top-K: gather segments + refinement + latent + DECODE ------
// Decode gathers f16 Wdec rows (half the traffic of f32; error ~1e-3 << thr).
__global__ __launch_bounds__(256) void topk_decode_kernel(
    const float2* __restrict__ cand_seg, const int* __restrict__ cntt,
    int* __restrict__ flags,
    float* __restrict__ latent0, float* __restrict__ latent1,
    float* __restrict__ recon0, float* __restrict__ recon1,
    const float* __restrict__ X0, const float* __restrict__ X1,
    const float* __restrict__ WT0, const float* __restrict__ WT1,
    const float* __restrict__ be0, const float* __restrict__ be1,
    const ushort* __restrict__ Wd0, const ushort* __restrict__ Wd1,
    const float* __restrict__ bd0, const float* __restrict__ bd1) {
  __shared__ float    sval[CAND_CAP];
  __shared__ int      sidx[CAND_CAP];
  __shared__ uint32_t hist[2048];
  __shared__ uint32_t chunkS[256];
  __shared__ int      tcnt[NT], toff[NT];
  __shared__ float    swval[WCAP];
  __shared__ int      swidx[WCAP];
  __shared__ double   wexact[WCAP];
  __shared__ float    sel_val[K_TOP];
  __shared__ int      sel_idx[K_TOP];
  __shared__ uint32_t s_d, s_ab;
  __shared__ int      s_n, s_ndef, s_nw, s_bad;

  const int tid  = threadIdx.x;
  const int grow = blockIdx.x;
  const int strm = grow >> 12;
  const int row  = grow & (B_ROWS - 1);

  float* latent = strm ? latent1 : latent0;
  float* recon  = strm ? recon1 : recon0;
  const float* X    = strm ? X1 : X0;
  const float* WT   = strm ? WT1 : WT0;
  const float* benc = strm ? be1 : be0;
  const ushort* Wdec = strm ? Wd1 : Wd0;
  const float* bdec = strm ? bd1 : bd0;

  // ---- per-tile counts (contiguous 64 ints) -> shuffle prefix sum ----
  if (tid < NT) tcnt[tid] = cntt[(size_t)grow * NT + tid];
  __syncthreads();
  if (tid < NT) {
    int v = tcnt[tid];
    int inc = v;
#pragma unroll
    for (int off = 1; off < 64; off <<= 1) {
      int u = __shfl_up(inc, off);
      if (tid >= off) inc += u;
    }
    toff[tid] = inc - v;
    if (tid == NT - 1) s_n = inc;
  }
  __syncthreads();
  const int n = s_n;

  if (n < K_TOP || n > CAND_CAP) {
    if (tid == 0) flags[grow] = 1;
    return;
  }

  // ---- gather: 4 threads per tile; row's 64 segments are contiguous 16KB ----
  {
    const int t2 = tid >> 2;
    const int c = tcnt[t2], o = toff[t2];
    const float2* src = cand_seg + ((size_t)grow * NT + t2) * SLOT;
    for (int k = tid & 3; k < c; k += 4) {
      const float2 e = src[k];
      sval[o + k] = e.x;
      sidx[o + k] = __float_as_int(e.y);
    }
  }
  __syncthreads();

  // ---- 2-level radix on candidate f32 bits (all values >= TAU > 0) ----
  uint32_t prefTop = 0, d1 = 0, needL = K_TOP;
#pragma unroll 1
  for (int level = 0; level < 2; ++level) {
    const int shift = level ? 9 : 20;
    for (int b = tid; b < 2048; b += 256) hist[b] = 0;
    __syncthreads();
    for (int i = tid; i < n; i += 256) {
      const uint32_t k = __float_as_uint(sval[i]);
      if (level == 0 || (k >> 20) == prefTop)
        atomicAdd(&hist[(k >> shift) & 2047], 1u);
    }
    __syncthreads();
    uint32_t cs = 0;
#pragma unroll
    for (int c = 0; c < 8; ++c) cs += hist[tid * 8 + c];
    chunkS[tid] = cs;
    __syncthreads();
    for (int off = 1; off < 256; off <<= 1) {
      const uint32_t v = (tid + off < 256) ? chunkS[tid + off] : 0u;
      __syncthreads();
      chunkS[tid] += v;
      __syncthreads();
    }
    {
      uint32_t cum = (tid + 1 < 256) ? chunkS[tid + 1] : 0u;
#pragma unroll
      for (int c = 7; c >= 0; --c) {
        const int bb = tid * 8 + c;
        const uint32_t nxt = cum;
        cum += hist[bb];
        if (cum >= needL && nxt < needL) { s_d = (uint32_t)bb; s_ab = nxt; }
      }
    }
    __syncthreads();
    if (level == 0) { prefTop = s_d; needL = needL - s_ab; }
    else            { d1 = s_d; }
    __syncthreads();
  }

  const uint32_t blo_bits = (prefTop << 20) | (d1 << 9);
  const float Tlo = __uint_as_float(blo_bits);
  const float Thi = __uint_as_float(blo_bits + 512u);
  const float Tp = Thi + TK_DELTA;
  const float Tm = Tlo - TK_DELTA;

  if (Tm < TAU) {
    if (tid == 0) flags[grow] = 1;
    return;
  }

  // ---- classify candidates: definite-in / window ----
  if (tid == 0) { s_ndef = 0; s_nw = 0; s_bad = 0; }
  __syncthreads();
  for (int i = tid; i < n; i += 256) {
    const float v = sval[i];
    if (v > Tp) {
      const int pos = atomicAdd(&s_ndef, 1);
      if (pos < K_TOP) { sel_val[pos] = v; sel_idx[pos] = sidx[i]; }
      else             { s_bad = 1; }
    } else if (v >= Tm) {
      const int pos = atomicAdd(&s_nw, 1);
      if (pos < WCAP) { swval[pos] = v; swidx[pos] = sidx[i]; }
      else            { s_bad = 1; }
    }
  }
  __syncthreads();
  const int ndef = s_ndef;
  const int nw   = s_nw;
  if (s_bad || ndef >= K_TOP) {
    if (tid == 0) flags[grow] = 1;
    return;
  }
  const int r = K_TOP - ndef;     // >= 1

  // ---- exact f64 refinement of window members ----
  {
    const int wv = tid >> 6, ln = tid & 63;
    const float* xr = X + (size_t)row * D_IN;
    for (int c = wv; c < nw; c += 4) {
      const float* wrp = WT + (size_t)swidx[c] * D_IN;
      double a = 0.0;
#pragma unroll
      for (int j = 0; j < 16; ++j)
        a += (double)xr[ln + 64 * j] * (double)wrp[ln + 64 * j];
#pragma unroll
      for (int off = 32; off; off >>= 1) a += __shfl_xor(a, off);
      if (ln == 0) wexact[c] = a + (double)benc[swidx[c]];
    }
  }
  __syncthreads();
  // rank window by (exact desc, index asc) = jax tie-break; take top r
  if (tid < nw) {
    const double ei = wexact[tid];
    const int    ii = swidx[tid];
    int rank = 0;
    for (int j = 0; j < nw; ++j) {
      const double ej = wexact[j];
      const int    ij = swidx[j];
      rank += (ej > ei) || (ej == ei && ij < ii);
    }
    if (rank < r) { sel_val[ndef + rank] = swval[tid]; sel_idx[ndef + rank] = ii; }
  }
  __syncthreads();

  // ---- dense latent row: zeros + 32 selected ----
  float* rowp = latent + (size_t)row * H_HID;
  const float4 z4 = make_float4(0.f, 0.f, 0.f, 0.f);
  for (int i4 = tid; i4 < H_HID / 4; i4 += 256)
    reinterpret_cast<float4*>(rowp)[i4] = z4;
  __syncthreads();   // zeros complete BEFORE scatter
  if (tid < K_TOP) rowp[sel_idx[tid]] = sel_val[tid];

  // ---- fused decode: recon = b_dec + sum_k val_k * Wd16[idx_k, :] ----
  const float4 b4 = reinterpret_cast<const float4*>(bdec)[tid];
  float ax = b4.x, ay = b4.y, az = b4.z, aw = b4.w;
#pragma unroll 1
  for (int k = 0; k < K_TOP; ++k) {
    const float v = sel_val[k];
    const uint2 w2 = reinterpret_cast<const uint2*>(Wdec + (size_t)sel_idx[k] * D_IN)[tid];
    const float2 f01 = __half22float2(*reinterpret_cast<const __half2*>(&w2.x));
    const float2 f23 = __half22float2(*reinterpret_cast<const __half2*>(&w2.y));
    ax = fmaf(v, f01.x, ax);
    ay = fmaf(v, f01.y, ay);
    az = fmaf(v, f23.x, az);
    aw = fmaf(v, f23.y, aw);
  }
  reinterpret_cast<float4*>(recon + (size_t)row * D_IN)[tid] = make_float4(ax, ay, az, aw);
}

// ---------------- exact fallback (expected-never path) ----------------
__global__ __launch_bounds__(256) void fallback_kernel(
    const int* __restrict__ flags,
    const float* __restrict__ X0, const float* __restrict__ X1,
    const float* __restrict__ WT0, const float* __restrict__ WT1,
    const float* __restrict__ be0, const float* __restrict__ be1,
    float* __restrict__ latent0, float* __restrict__ latent1,
    float* __restrict__ recon0, float* __restrict__ recon1,
    const ushort* __restrict__ Wd0, const ushort* __restrict__ Wd1,
    const float* __restrict__ bd0, const float* __restrict__ bd1) {
  extern __shared__ double sc[];   // [H_HID] doubles = 128 KB dynamic
  __shared__ double rb[256];
  __shared__ int    ri[256];
  __shared__ float  fsel_val[K_TOP];
  __shared__ int    fsel_idx[K_TOP];
  const int grow = blockIdx.x;
  if (flags[grow] == 0) return;
  const int strm = grow >> 12;
  const int row  = grow & (B_ROWS - 1);
  const int tid = threadIdx.x;
  const float* X    = strm ? X1 : X0;
  const float* WT   = strm ? WT1 : WT0;
  const float* benc = strm ? be1 : be0;
  float* latent = strm ? latent1 : latent0;
  float* recon  = strm ? recon1 : recon0;
  const ushort* Wdec = strm ? Wd1 : Wd0;
  const float* bdec = strm ? bd1 : bd0;

  const float* xr = X + (size_t)row * D_IN;
  for (int c = tid; c < H_HID; c += 256) {
    const float* wrp = WT + (size_t)c * D_IN;
    double a = (double)benc[c];
    for (int j = 0; j < D_IN; ++j)
      a += (double)xr[j] * (double)wrp[j];
    sc[c] = fmax(a, 0.0);   // relu
  }
  float* rowp = latent + (size_t)row * H_HID;
  for (int i = tid; i < H_HID; i += 256) rowp[i] = 0.0f;
  __syncthreads();
#pragma unroll 1
  for (int k = 0; k < K_TOP; ++k) {
    double bv = -1.0; int bi = H_HID;
    for (int c = tid; c < H_HID; c += 256) {
      const double v = sc[c];
      if (v > bv || (v == bv && c < bi)) { bv = v; bi = c; }
    }
    rb[tid] = bv; ri[tid] = bi;
    __syncthreads();
    for (int off = 128; off; off >>= 1) {
      if (tid < off) {
        if (rb[tid + off] > rb[tid] ||
            (rb[tid + off] == rb[tid] && ri[tid + off] < ri[tid])) {
          rb[tid] = rb[tid + off]; ri[tid] = ri[tid + off];
        }
      }
      __syncthreads();
    }
    if (tid == 0) {
      const int ii = ri[0];
      const float vv = (float)rb[0];
      fsel_val[k] = vv; fsel_idx[k] = ii;
      rowp[ii] = vv;
      sc[ii] = -1.0;
    }
    __syncthreads();
  }
  const float4 b4 = reinterpret_cast<const float4*>(bdec)[tid];
  float ax = b4.x, ay = b4.y, az = b4.z, aw = b4.w;
#pragma unroll 1
  for (int k = 0; k < K_TOP; ++k) {
    const float v = fsel_val[k];
    const uint2 w2 = reinterpret_cast<const uint2*>(Wdec + (size_t)fsel_idx[k] * D_IN)[tid];
    const float2 f01 = __half22float2(*reinterpret_cast<const __half2*>(&w2.x));
    const float2 f23 = __half22float2(*reinterpret_cast<const __half2*>(&w2.y));
    ax = fmaf(v, f01.x, ax);
    ay = fmaf(v, f01.y, ay);
    az = fmaf(v, f23.x, az);
    aw = fmaf(v, f23.y, aw);
  }
  reinterpret_cast<float4*>(recon + (size_t)row * D_IN)[tid] = make_float4(ax, ay, az, aw);
}

// ---------------- launch ----------------

extern "C" void kernel_launch(void* const* d_in, const int* in_sizes, int n_in,
                              void* d_out, int out_size, void* d_ws, size_t ws_size,
                              hipStream_t stream) {
  (void)in_sizes; (void)n_in; (void)out_size; (void)ws_size;
  const float* Xv     = (const float*)d_in[0];
  const float* Xt     = (const float*)d_in[1];
  const float* Wv_enc = (const float*)d_in[2];
  const float* bv_enc = (const float*)d_in[3];
  const float* Wt_enc = (const float*)d_in[4];
  const float* bt_enc = (const float*)d_in[5];
  const float* Wv_dec = (const float*)d_in[6];
  const float* bv_dec = (const float*)d_in[7];
  const float* Wt_dec = (const float*)d_in[8];
  const float* bt_dec = (const float*)d_in[9];

  float* out      = (float*)d_out;
  float* recon_v  = out;
  float* recon_t  = out + (size_t)B_ROWS * D_IN;
  float* latent_v = out + 2ull * B_ROWS * D_IN;
  float* latent_t = latent_v + (size_t)B_ROWS * H_HID;

  char* ws = (char*)d_ws;
  const size_t szA = (size_t)B_ROWS * D_IN;    // 4M elems
  const size_t szB = (size_t)H_HID * D_IN;     // 16M elems
  ushort* Ah_v  = (ushort*)ws;
  ushort* Ah_t  = Ah_v + szA;
  ushort* Bh_v  = Ah_t + szA;
  ushort* Bh_t  = Bh_v + szB;
  float*  WT32_v = (float*)(Bh_t + szB);
  float*  WT32_t = WT32_v + szB;
  ushort* Wd16_v = (ushort*)(WT32_t + szB);    // 32 MB
  ushort* Wd16_t = Wd16_v + szB;               // 32 MB
  float2* cand_seg = (float2*)(Wd16_t + szB);  // [GROWS][NT][SLOT] = 134 MB
  int*    cntt  = (int*)(cand_seg + (size_t)NT * GROWS * SLOT);  // [GROWS][NT]
  int*    flags = cntt + (size_t)NT * GROWS;   // [GROWS] (contiguous for zeroing)

  hipFuncSetAttribute((const void*)gemm_enc_8ph,
                      hipFuncAttributeMaxDynamicSharedMemorySize, 131072);
  hipFuncSetAttribute((const void*)fallback_kernel,
                      hipFuncAttributeMaxDynamicSharedMemorySize, 131072);

  // fused prep: W split/transpose + X split + zero + Wdec->f16 (one dispatch)
  prep_kernel<<<59424, 256, 0, stream>>>(Wv_enc, Wt_enc, Bh_v, Bh_t, WT32_v, WT32_t,
                                         Xv, Xt, Ah_v, Ah_t, cntt,
                                         Wv_dec, Wt_dec, Wd16_v, Wd16_t);

  // encoder GEMMs (both streams, XCD-paired persistent blocks, single round)
  gemm_enc_8ph<<<256, 512, 131072, stream>>>(Ah_v, Ah_t, Bh_v, Bh_t,
                                             bv_enc, bt_enc, cand_seg, cntt, flags);

  // top-K + refinement + latent + fused decode (f16 Wdec gather)
  topk_decode_kernel<<<2 * B_ROWS, 256, 0, stream>>>(
      cand_seg, cntt, flags, latent_v, latent_t, recon_v, recon_t,
      Xv, Xt, WT32_v, WT32_t, bv_enc, bt_enc,
      Wd16_v, Wd16_t, bv_dec, bt_dec);

  // exact fallback for flagged rows (expected none)
  fallback_kernel<<<2 * B_ROWS, 256, 131072, stream>>>(
      flags, Xv, Xt, WT32_v, WT32_t, bv_enc, bt_enc,
      latent_v, latent_t, recon_v, recon_t,
      Wd16_v, Wd16_t, bv_dec, bt_dec);
}

// Round 17
// 677.297 us; speedup vs baseline: 1.0594x; 1.0594x over previous
//
#include <hip/hip_runtime.h>
#include <hip/hip_fp16.h>
#include <stdint.h>

#define B_ROWS 4096
#define D_IN   1024
#define H_HID  16384
#define K_TOP  32

#define NT       64       // H_HID/256 tn-tiles per row
#define GROWS    8192     // 2*B_ROWS
#define SLOT     32       // per-(row, tn-tile) fixed segment slots (mean 10.7, s 3.2)
#define CAND_CAP 1536     // per-row gathered candidate cap (mean 682, s 26)
#define TAU      1.0f     // fixed candidate threshold; safety via flags+fallback
#define TK_DELTA 1e-2f    // refinement window half-width (>= 2x 12-sigma h~ error)
#define WCAP     256

typedef __attribute__((ext_vector_type(8))) _Float16 half8;
typedef __attribute__((ext_vector_type(4))) float    f32x4;

// ---------------- helpers ----------------

__device__ __forceinline__ ushort hi16(float x) {
  return (fabsf(x) >= 0x1p-14f) ? __half_as_ushort(__float2half(x)) : (ushort)0;
}

__device__ __forceinline__ void gload_lds16(const void* g, void* l) {
  __builtin_amdgcn_global_load_lds(
      (const __attribute__((address_space(1))) void*)g,
      (__attribute__((address_space(3))) void*)l, 16, 0, 0);
}

// ---------------- fused prep: split_wt + split_a + counter zero ----------------
// grid: [0, 32768) split_wt | [32768, 40960) split_a | [40960, 43040) zero
__global__ __launch_bounds__(256) void prep_kernel(
    const float* __restrict__ W0, const float* __restrict__ W1,
    ushort* __restrict__ hiT0, ushort* __restrict__ hiT1,
    float* __restrict__ wT0, float* __restrict__ wT1,
    const float* __restrict__ x0, const float* __restrict__ x1,
    ushort* __restrict__ hiA0, ushort* __restrict__ hiA1,
    int* __restrict__ zbase) {
  __shared__ float tile[32][33];
  const int b = blockIdx.x;
  const int tid = threadIdx.x;
  if (b < 32768) {                      // ---- W transpose + split ----
    const int s  = b >> 14;
    const int b2 = b & 16383;           // 512 x 32
    const float* W = s ? W1 : W0;
    ushort* hiT = s ? hiT1 : hiT0;
    float*  wT32 = s ? wT1 : wT0;
    const int c0 = (b2 & 511) * 32;
    const int r0 = (b2 >> 9) * 32;
    const int tx = tid & 31;
    const int ty = tid >> 5;
#pragma unroll
    for (int i = 0; i < 32; i += 8)
      tile[ty + i][tx] = W[(size_t)(r0 + ty + i) * H_HID + c0 + tx];
    __syncthreads();
#pragma unroll
    for (int i = 0; i < 32; i += 8) {
      float v = tile[tx][ty + i];
      size_t o = (size_t)(c0 + ty + i) * D_IN + r0 + tx;
      hiT[o]  = hi16(v);
      wT32[o] = v;
    }
  } else if (b < 40960) {               // ---- X split ----
    const int idx = b - 32768;          // 0..8191; 4096 per stream
    const int s = idx >> 12;
    const float* x = s ? x1 : x0;
    ushort* hi = s ? hiA1 : hiA0;
    const int t = (idx & 4095) * 256 + tid;
    const int base = t * 4;
    float4 v = *reinterpret_cast<const float4*>(x + base);
    ushort4 h;
    h.x = hi16(v.x); h.y = hi16(v.y); h.z = hi16(v.z); h.w = hi16(v.w);
    *reinterpret_cast<ushort4*>(hi + base) = h;
  } else {                              // ---- zero cntt+flags (532480 ints) ----
    const int idx = (b - 40960) * 256 + tid;
    zbase[idx] = 0;
  }
}

// ---------------- encoder GEMM: 256x256 tiles, 8-phase, persistent J=8 -------
// (frozen: identical to R15 -- XCD-paired mapping, counted-vmcnt ledger)
#define NTILES 16   // 1024 / 64
#define JTILES 8

__global__ __launch_bounds__(512, 2) void gemm_enc_8ph(const ushort* __restrict__ Ah0,
                                                       const ushort* __restrict__ Ah1,
                                                       const ushort* __restrict__ Bh0,
                                                       const ushort* __restrict__ Bh1,
                                                       const float* __restrict__ bias0,
                                                       const float* __restrict__ bias1,
                                                       float2* __restrict__ cand_seg,
                                                       int* __restrict__ cntt,
                                                       int* __restrict__ flags) {
  extern __shared__ ushort smem[];   // [2][32768]: buf*32768, B-half at +16384
  __shared__ int lcnt[256];          // epilogue row counters (static, +1KB)
  const int tid  = threadIdx.x;
  const int wid  = tid >> 6;
  const int lane = tid & 63;
  const int wr   = wid >> 2;
  const int wc   = wid & 3;
  // XCD-paired decode: 4 (strm,tm) pairs per XCD, 8 tng blocks per pair
  const int xcd  = blockIdx.x & 7;
  const int slot = blockIdx.x >> 3;            // 0..31
  const int pair = xcd * 4 + (slot >> 3);      // 0..31 distinct (strm,tm)
  const int strm = pair >> 4;
  const int tm   = pair & 15;
  const int tng  = slot & 7;                   // 0..7 (group of 8 tn)
  const ushort* Ah = strm ? Ah1 : Ah0;
  const ushort* Bh = strm ? Bh1 : Bh0;
  const float* bias = strm ? bias1 : bias0;
  const int rowA0 = tm * 256;

  const int st_row = wid * 8 + (lane >> 3);
  const int st_lin = lane & 7;
  const int st_src = (lane & 7) ^ ((lane >> 3) & 7);
  const int fr   = lane & 15;
  const int fk   = lane >> 4;
  const int swz8 = (lane & 7) << 3;

  f32x4 acc[8][4];
#pragma unroll
  for (int i = 0; i < 8; ++i)
#pragma unroll
    for (int j = 0; j < 4; ++j) {
      f32x4 z = {0.f, 0.f, 0.f, 0.f};
      acc[i][j] = z;
    }
  half8 a[4][2], b[4][2];

#define DS_A(MH)                                                            \
  _Pragma("unroll") for (int m = 0; m < 4; ++m)                             \
  _Pragma("unroll") for (int k = 0; k < 2; ++k) {                           \
    const int r = wr * 128 + ((MH) * 4 + m) * 16 + fr;                      \
    const int idx = (r * 64 + k * 32 + fk * 8) ^ swz8;                      \
    a[m][k] = *reinterpret_cast<const half8*>(Acur + idx);                  \
  }
#define DS_B(NH)                                                            \
  _Pragma("unroll") for (int n = 0; n < 2; ++n)                             \
  _Pragma("unroll") for (int k = 0; k < 2; ++k) {                           \
    const int r = wc * 64 + ((NH) * 2 + n) * 16 + fr;                       \
    const int idx = (r * 64 + k * 32 + fk * 8) ^ swz8;                      \
    b[(NH) * 2 + n][k] = *reinterpret_cast<const half8*>(Bcur + idx);       \
  }
#define MFMA_PH(MH, NH)                                                     \
  __builtin_amdgcn_s_setprio(1);                                            \
  _Pragma("unroll") for (int m = 0; m < 4; ++m)                             \
  _Pragma("unroll") for (int n = 0; n < 2; ++n)                             \
  _Pragma("unroll") for (int k = 0; k < 2; ++k)                             \
    acc[(MH) * 4 + m][(NH) * 2 + n] = __builtin_amdgcn_mfma_f32_16x16x32_f16( \
        a[m][k], b[(NH) * 2 + n][k], acc[(MH) * 4 + m][(NH) * 2 + n], 0, 0, 0); \
  __builtin_amdgcn_s_setprio(0);
#define STAGE_A(Q)                                                          \
  gload_lds16(Ah + (size_t)(rowA0 + (Q) * 64 + st_row) * 1024 + st_k0 + st_src * 8, \
              Lnxt + ((Q) * 64 + st_row) * 64 + st_lin * 8)
#define STAGE_B(Q)                                                          \
  gload_lds16(Bh + (size_t)(st_rowB0 + (Q) * 64 + st_row) * 1024 + st_k0 + st_src * 8, \
              Lnxt + 16384 + ((Q) * 64 + st_row) * 64 + st_lin * 8)
#define BAR() __builtin_amdgcn_s_barrier()

  // prologue: stage (j=0, t=0) into buf0.  Order: Bq0..3, Aq0, Aq2, Aq1, Aq3.
  {
    const int st_k0 = 0;
    const int st_rowB0 = tng * 8 * 256;
    ushort* Lnxt = smem;
    STAGE_B(0); STAGE_B(1); STAGE_B(2); STAGE_B(3);
    STAGE_A(0); STAGE_A(2); STAGE_A(1); STAGE_A(3);
  }
  asm volatile("s_waitcnt vmcnt(2)" ::: "memory");
  BAR();

#pragma unroll 1
  for (int jt = 0; jt < JTILES * NTILES; ++jt) {
    const int t = jt & (NTILES - 1);
    const int j = jt >> 4;
    const int cur = t & 1;                     // NTILES even -> parity by t
    const ushort* Acur = smem + cur * 32768;
    const ushort* Bcur = Acur + 16384;
    ushort* Lnxt = smem + (cur ^ 1) * 32768;
    int tt = t + 1, jn = j;
    if (tt == NTILES) { tt = 0; jn = j + 1; }
    const bool hn = (jn < JTILES);
    const int st_k0 = tt << 6;
    const int st_rowB0 = (tng * 8 + jn) * 256;

    // phase 1
    DS_A(0); DS_B(0);
    if (hn) { STAGE_B(0); STAGE_B(1); }
    BAR();
    MFMA_PH(0, 0);
    BAR();
    // phase 2
    DS_B(1);
    if (hn) { STAGE_B(2); STAGE_B(3); }
    BAR();
    MFMA_PH(0, 1);
    asm volatile("s_waitcnt vmcnt(4)" ::: "memory");
    BAR();
    // phase 3
    DS_A(1);
    if (hn) { STAGE_A(0); STAGE_A(2); }
    BAR();
    MFMA_PH(1, 0);
    BAR();
    // phase 4
    if (hn) { STAGE_A(1); STAGE_A(3); }
    BAR();
    MFMA_PH(1, 1);
    asm volatile("s_waitcnt vmcnt(2)" ::: "memory");
    BAR();

    if (t == NTILES - 1) {
      // ---- candidate epilogue for tile (tm, tn = tng*8+j) ----
      const int tn = tng * 8 + j;
      float2* lcand = reinterpret_cast<float2*>(smem + 32768);  // [SLOT][256]
      if (tid < 256) lcnt[tid] = 0;
      __syncthreads();

      const int ccol = lane & 15;
      const int crow = (lane >> 4) * 4;
#pragma unroll
      for (int jj = 0; jj < 4; ++jj) {
        const int col = tn * 256 + wc * 64 + jj * 16 + ccol;
        const float bv = bias[col];
#pragma unroll
        for (int i = 0; i < 8; ++i) {
          const int lrow0 = wr * 128 + i * 16 + crow;
#pragma unroll
          for (int p = 0; p < 4; ++p) {
            const float v = acc[i][jj][p] + bv;
            if (v >= TAU) {
              const int lrow = lrow0 + p;
              const int pos = atomicAdd(&lcnt[lrow], 1);   // LDS atomic only
              if (pos < SLOT)
                lcand[pos * 256 + lrow] = make_float2(v, __int_as_float(col));
            }
          }
        }
      }
      __syncthreads();

      if (tid < 256) {
        int c = lcnt[tid];
        const int grow = strm * B_ROWS + rowA0 + tid;
        if (c > SLOT) { flags[grow] = 1; c = SLOT; }
        const size_t seg = (size_t)grow * NT + tn;       // [grow][tn] layout
        cntt[seg] = c;                                   // plain store
        float2* dst = cand_seg + seg * SLOT;
        for (int k = 0; k < c; ++k) dst[k] = lcand[k * 256 + tid];
      }
      // reset accumulators for the next tile
#pragma unroll
      for (int i = 0; i < 8; ++i)
#pragma unroll
        for (int jj = 0; jj < 4; ++jj) {
          f32x4 z = {0.f, 0.f, 0.f, 0.f};
          acc[i][jj] = z;
        }
      __syncthreads();   // lcand reads done before buf1 is restaged (next t=0 ph1)
    }
  }
#undef DS_A
#undef DS_B
#undef MFMA_PH
#undef STAGE_A
#undef STAGE_B
#undef BAR
}

// ---------------- top-K: gather segments + refinement + latent + DECODE ------
// Latent ZERO-FILL issued at kernel START (fire-and-forget stores overlap the
// selection work); pre-scatter vmcnt(0)+barrier orders zeros before scatter.
__global__ __launch_bounds__(256) void topk_decode_kernel(
    const float2* __restrict__ cand_seg, const int* __restrict__ cntt,
    int* __restrict__ flags,
    float* __restrict__ latent0, float* __restrict__ latent1,
    float* __restrict__ recon0, float* __restrict__ recon1,
    const float* __restrict__ X0, const float* __restrict__ X1,
    const float* __restrict__ WT0, const float* __restrict__ WT1,
    const float* __restrict__ be0, const float* __restrict__ be1,
    const float* __restrict__ Wd0, const float* __restrict__ Wd1,
    const float* __restrict__ bd0, const float* __restrict__ bd1) {
  __shared__ float    sval[CAND_CAP];
  __shared__ int      sidx[CAND_CAP];
  __shared__ uint32_t hist[2048];
  __shared__ uint32_t chunkS[256];
  __shared__ int      tcnt[NT], toff[NT];
  __shared__ float    swval[WCAP];
  __shared__ int      swidx[WCAP];
  __shared__ double   wexact[WCAP];
  __shared__ float    sel_val[K_TOP];
  __shared__ int      sel_idx[K_TOP];
  __shared__ uint32_t s_d, s_ab;
  __shared__ int      s_n, s_ndef, s_nw, s_bad;

  const int tid  = threadIdx.x;
  const int grow = blockIdx.x;
  const int strm = grow >> 12;
  const int row  = grow & (B_ROWS - 1);

  float* latent = strm ? latent1 : latent0;
  float* recon  = strm ? recon1 : recon0;
  const float* X    = strm ? X1 : X0;
  const float* WT   = strm ? WT1 : WT0;
  const float* benc = strm ? be1 : be0;
  const float* Wdec = strm ? Wd1 : Wd0;
  const float* bdec = strm ? bd1 : bd0;

  // ---- EARLY latent zero-fill: stores fly while selection runs below ----
  float* rowp = latent + (size_t)row * H_HID;
  const float4 z4 = make_float4(0.f, 0.f, 0.f, 0.f);
#pragma unroll
  for (int i4 = 0; i4 < H_HID / 4 / 256; ++i4)
    reinterpret_cast<float4*>(rowp)[i4 * 256 + tid] = z4;

  // ---- per-tile counts (contiguous 64 ints) -> shuffle prefix sum ----
  if (tid < NT) tcnt[tid] = cntt[(size_t)grow * NT + tid];
  __syncthreads();
  if (tid < NT) {
    int v = tcnt[tid];
    int inc = v;
#pragma unroll
    for (int off = 1; off < 64; off <<= 1) {
      int u = __shfl_up(inc, off);
      if (tid >= off) inc += u;
    }
    toff[tid] = inc - v;
    if (tid == NT - 1) s_n = inc;
  }
  __syncthreads();
  const int n = s_n;

  if (n < K_TOP || n > CAND_CAP) {
    if (tid == 0) flags[grow] = 1;
    return;
  }

  // ---- gather: 4 threads per tile; row's 64 segments are contiguous 16KB ----
  {
    const int t2 = tid >> 2;
    const int c = tcnt[t2], o = toff[t2];
    const float2* src = cand_seg + ((size_t)grow * NT + t2) * SLOT;
    for (int k = tid & 3; k < c; k += 4) {
      const float2 e = src[k];
      sval[o + k] = e.x;
      sidx[o + k] = __float_as_int(e.y);
    }
  }
  __syncthreads();

  // ---- 2-level radix on candidate f32 bits (all values >= TAU > 0) ----
  uint32_t prefTop = 0, d1 = 0, needL = K_TOP;
#pragma unroll 1
  for (int level = 0; level < 2; ++level) {
    const int shift = level ? 9 : 20;
    for (int b = tid; b < 2048; b += 256) hist[b] = 0;
    __syncthreads();
    for (int i = tid; i < n; i += 256) {
      const uint32_t k = __float_as_uint(sval[i]);
      if (level == 0 || (k >> 20) == prefTop)
        atomicAdd(&hist[(k >> shift) & 2047], 1u);
    }
    __syncthreads();
    uint32_t cs = 0;
#pragma unroll
    for (int c = 0; c < 8; ++c) cs += hist[tid * 8 + c];
    chunkS[tid] = cs;
    __syncthreads();
    for (int off = 1; off < 256; off <<= 1) {
      const uint32_t v = (tid + off < 256) ? chunkS[tid + off] : 0u;
      __syncthreads();
      chunkS[tid] += v;
      __syncthreads();
    }
    {
      uint32_t cum = (tid + 1 < 256) ? chunkS[tid + 1] : 0u;
#pragma unroll
      for (int c = 7; c >= 0; --c) {
        const int bb = tid * 8 + c;
        const uint32_t nxt = cum;
        cum += hist[bb];
        if (cum >= needL && nxt < needL) { s_d = (uint32_t)bb; s_ab = nxt; }
      }
    }
    __syncthreads();
    if (level == 0) { prefTop = s_d; needL = needL - s_ab; }
    else            { d1 = s_d; }
    __syncthreads();
  }

  const uint32_t blo_bits = (prefTop << 20) | (d1 << 9);
  const float Tlo = __uint_as_float(blo_bits);
  const float Thi = __uint_as_float(blo_bits + 512u);
  const float Tp = Thi + TK_DELTA;
  const float Tm = Tlo - TK_DELTA;

  if (Tm < TAU) {
    if (tid == 0) flags[grow] = 1;
    return;
  }

  // ---- classify candidates: definite-in / window ----
  if (tid == 0) { s_ndef = 0; s_nw = 0; s_bad = 0; }
  __syncthreads();
  for (int i = tid; i < n; i += 256) {
    const float v = sval[i];
    if (v > Tp) {
      const int pos = atomicAdd(&s_ndef, 1);
      if (pos < K_TOP) { sel_val[pos] = v; sel_idx[pos] = sidx[i]; }
      else             { s_bad = 1; }
    } else if (v >= Tm) {
      const int pos = atomicAdd(&s_nw, 1);
      if (pos < WCAP) { swval[pos] = v; swidx[pos] = sidx[i]; }
      else            { s_bad = 1; }
    }
  }
  __syncthreads();
  const int ndef = s_ndef;
  const int nw   = s_nw;
  if (s_bad || ndef >= K_TOP) {
    if (tid == 0) flags[grow] = 1;
    return;
  }
  const int r = K_TOP - ndef;     // >= 1

  // ---- exact f64 refinement of window members ----
  {
    const int wv = tid >> 6, ln = tid & 63;
    const float* xr = X + (size_t)row * D_IN;
    for (int c = wv; c < nw; c += 4) {
      const float* wrp = WT + (size_t)swidx[c] * D_IN;
      double a = 0.0;
#pragma unroll
      for (int j = 0; j < 16; ++j)
        a += (double)xr[ln + 64 * j] * (double)wrp[ln + 64 * j];
#pragma unroll
      for (int off = 32; off; off >>= 1) a += __shfl_xor(a, off);
      if (ln == 0) wexact[c] = a + (double)benc[swidx[c]];
    }
  }
  __syncthreads();
  // rank window by (exact desc, index asc) = jax tie-break; take top r
  if (tid < nw) {
    const double ei = wexact[tid];
    const int    ii = swidx[tid];
    int rank = 0;
    for (int j = 0; j < nw; ++j) {
      const double ej = wexact[j];
      const int    ij = swidx[j];
      rank += (ej > ei) || (ej == ei && ij < ii);
    }
    if (rank < r) { sel_val[ndef + rank] = swval[tid]; sel_idx[ndef + rank] = ii; }
  }

  // ---- order early zeros before scatter: drain own stores, then barrier ----
  asm volatile("s_waitcnt vmcnt(0)" ::: "memory");
  __syncthreads();
  if (tid < K_TOP) rowp[sel_idx[tid]] = sel_val[tid];

  // ---- fused decode: recon = b_dec + sum_k val_k * Wdec[idx_k, :] ----
  const float4 b4 = reinterpret_cast<const float4*>(bdec)[tid];
  float ax = b4.x, ay = b4.y, az = b4.z, aw = b4.w;
#pragma unroll 4
  for (int k = 0; k < K_TOP; ++k) {
    const float v = sel_val[k];
    const float4 w = reinterpret_cast<const float4*>(Wdec + (size_t)sel_idx[k] * D_IN)[tid];
    ax = fmaf(v, w.x, ax);
    ay = fmaf(v, w.y, ay);
    az = fmaf(v, w.z, az);
    aw = fmaf(v, w.w, aw);
  }
  reinterpret_cast<float4*>(recon + (size_t)row * D_IN)[tid] = make_float4(ax, ay, az, aw);
}

// ---------------- exact fallback (expected-never path) ----------------
__global__ __launch_bounds__(256) void fallback_kernel(
    const int* __restrict__ flags,
    const float* __restrict__ X0, const float* __restrict__ X1,
    const float* __restrict__ WT0, const float* __restrict__ WT1,
    const float* __restrict__ be0, const float* __restrict__ be1,
    float* __restrict__ latent0, float* __restrict__ latent1,
    float* __restrict__ recon0, float* __restrict__ recon1,
    const float* __restrict__ Wd0, const float* __restrict__ Wd1,
    const float* __restrict__ bd0, const float* __restrict__ bd1) {
  extern __shared__ double sc[];   // [H_HID] doubles = 128 KB dynamic
  __shared__ double rb[256];
  __shared__ int    ri[256];
  __shared__ float  fsel_val[K_TOP];
  __shared__ int    fsel_idx[K_TOP];
  const int grow = blockIdx.x;
  if (flags[grow] == 0) return;
  const int strm = grow >> 12;
  const int row  = grow & (B_ROWS - 1);
  const int tid = threadIdx.x;
  const float* X    = strm ? X1 : X0;
  const float* WT   = strm ? WT1 : WT0;
  const float* benc = strm ? be1 : be0;
  float* latent = strm ? latent1 : latent0;
  float* recon  = strm ? recon1 : recon0;
  const float* Wdec = strm ? Wd1 : Wd0;
  const float* bdec = strm ? bd1 : bd0;

  const float* xr = X + (size_t)row * D_IN;
  for (int c = tid; c < H_HID; c += 256) {
    const float* wrp = WT + (size_t)c * D_IN;
    double a = (double)benc[c];
    for (int j = 0; j < D_IN; ++j)
      a += (double)xr[j] * (double)wrp[j];
    sc[c] = fmax(a, 0.0);   // relu
  }
  float* rowp = latent + (size_t)row * H_HID;
  for (int i = tid; i < H_HID; i += 256) rowp[i] = 0.0f;
  __syncthreads();
#pragma unroll 1
  for (int k = 0; k < K_TOP; ++k) {
    double bv = -1.0; int bi = H_HID;
    for (int c = tid; c < H_HID; c += 256) {
      const double v = sc[c];
      if (v > bv || (v == bv && c < bi)) { bv = v; bi = c; }
    }
    rb[tid] = bv; ri[tid] = bi;
    __syncthreads();
    for (int off = 128; off; off >>= 1) {
      if (tid < off) {
        if (rb[tid + off] > rb[tid] ||
            (rb[tid + off] == rb[tid] && ri[tid + off] < ri[tid])) {
          rb[tid] = rb[tid + off]; ri[tid] = ri[tid + off];
        }
      }
      __syncthreads();
    }
    if (tid == 0) {
      const int ii = ri[0];
      const float vv = (float)rb[0];
      fsel_val[k] = vv; fsel_idx[k] = ii;
      rowp[ii] = vv;
      sc[ii] = -1.0;
    }
    __syncthreads();
  }
  const float4 b4 = reinterpret_cast<const float4*>(bdec)[tid];
  float ax = b4.x, ay = b4.y, az = b4.z, aw = b4.w;
#pragma unroll 1
  for (int k = 0; k < K_TOP; ++k) {
    const float v = fsel_val[k];
    const float4 w = reinterpret_cast<const float4*>(Wdec + (size_t)fsel_idx[k] * D_IN)[tid];
    ax = fmaf(v, w.x, ax);
    ay = fmaf(v, w.y, ay);
    az = fmaf(v, w.z, az);
    aw = fmaf(v, w.w, aw);
  }
  reinterpret_cast<float4*>(recon + (size_t)row * D_IN)[tid] = make_float4(ax, ay, az, aw);
}

// ---------------- launch ----------------

extern "C" void kernel_launch(void* const* d_in, const int* in_sizes, int n_in,
                              void* d_out, int out_size, void* d_ws, size_t ws_size,
                              hipStream_t stream) {
  (void)in_sizes; (void)n_in; (void)out_size; (void)ws_size;
  const float* Xv     = (const float*)d_in[0];
  const float* Xt     = (const float*)d_in[1];
  const float* Wv_enc = (const float*)d_in[2];
  const float* bv_enc = (const float*)d_in[3];
  const float* Wt_enc = (const float*)d_in[4];
  const float* bt_enc = (const float*)d_in[5];
  const float* Wv_dec = (const float*)d_in[6];
  const float* bv_dec = (const float*)d_in[7];
  const float* Wt_dec = (const float*)d_in[8];
  const float* bt_dec = (const float*)d_in[9];

  float* out      = (float*)d_out;
  float* recon_v  = out;
  float* recon_t  = out + (size_t)B_ROWS * D_IN;
  float* latent_v = out + 2ull * B_ROWS * D_IN;
  float* latent_t = latent_v + (size_t)B_ROWS * H_HID;

  char* ws = (char*)d_ws;
  const size_t szA = (size_t)B_ROWS * D_IN;    // 4M elems
  const size_t szB = (size_t)H_HID * D_IN;     // 16M elems
  ushort* Ah_v  = (ushort*)ws;
  ushort* Ah_t  = Ah_v + szA;
  ushort* Bh_v  = Ah_t + szA;
  ushort* Bh_t  = Bh_v + szB;
  float*  WT32_v = (float*)(Bh_t + szB);
  float*  WT32_t = WT32_v + szB;
  float2* cand_seg = (float2*)(WT32_t + szB);  // [GROWS][NT][SLOT] = 134 MB
  int*    cntt  = (int*)(cand_seg + (size_t)NT * GROWS * SLOT);  // [GROWS][NT]
  int*    flags = cntt + (size_t)NT * GROWS;   // [GROWS] (contiguous for zeroing)

  hipFuncSetAttribute((const void*)gemm_enc_8ph,
                      hipFuncAttributeMaxDynamicSharedMemorySize, 131072);
  hipFuncSetAttribute((const void*)fallback_kernel,
                      hipFuncAttributeMaxDynamicSharedMemorySize, 131072);

  // fused prep: W split/transpose + X split + cntt/flags zero (one dispatch)
  prep_kernel<<<43040, 256, 0, stream>>>(Wv_enc, Wt_enc, Bh_v, Bh_t, WT32_v, WT32_t,
                                         Xv, Xt, Ah_v, Ah_t, cntt);

  // encoder GEMMs (both streams, XCD-paired persistent blocks, single round)
  gemm_enc_8ph<<<256, 512, 131072, stream>>>(Ah_v, Ah_t, Bh_v, Bh_t,
                                             bv_enc, bt_enc, cand_seg, cntt, flags);

  // top-K + refinement + latent + fused decode (both streams)
  topk_decode_kernel<<<2 * B_ROWS, 256, 0, stream>>>(
      cand_seg, cntt, flags, latent_v, latent_t, recon_v, recon_t,
      Xv, Xt, WT32_v, WT32_t, bv_enc, bt_enc,
      Wv_dec, Wt_dec, bv_dec, bt_dec);

  // exact fallback for flagged rows (expected none)
  fallback_kernel<<<2 * B_ROWS, 256, 131072, stream>>>(
      flags, Xv, Xt, WT32_v, WT32_t, bv_enc, bt_enc,
      latent_v, latent_t, recon_v, recon_t,
      Wv_dec, Wt_dec, bv_dec, bt_dec);
}